// Round 12
// baseline (528.059 us; speedup 1.0000x reference)
//
#include <hip/hip_runtime.h>
#include <math.h>

#define D    6
#define S    128
#define H    128
#define WIN  16
#define BB   8
#define TT   513
#define NW   32
#define OUTD 10

// ---- device-global scratch ----
__device__ float g_lvl1[BB * NW * D];
__device__ float g_area[BB * NW * D * D];
__device__ float g_h0[BB * S];
__device__ float g_hist[BB * (NW + 1) * S];

__device__ __forceinline__ float sp(float x) {
    return (x > 20.f) ? x : log1pf(expf(x));
}
__device__ __forceinline__ float sigm(float x) {
    return 1.f / (1.f + expf(-x));
}
__device__ __forceinline__ float dot4(float4 a, float4 b, float acc) {
    return fmaf(a.x, b.x, fmaf(a.y, b.y, fmaf(a.z, b.z, fmaf(a.w, b.w, acc))));
}

// ---- LDS layout (float offsets) ----
#define O_W0   0        // [128 r][128 k] fp32 row-major
#define O_W1   16384    // -> 32768
#define O_U1   32768    // u1 [128]
#define O_SG1  32896
#define O_U2   33024
#define O_SG2  33152
#define O_V    33280    // [768]
#define O_U    34048    // [6][128]: U tangents, then T2
#define O_TB   34816    // [6][128]: T1, then bterm [768]
#define O_H    35584    // h double buffer [2][128]
#define O_B0   35840
#define O_B1   35968
#define O_B2   36096    // [768]
#define O_SIG  36864    // [2][44]
#define SMTOT  36952    // 147,808 B

// ---- K2: windowed log-signature + init MLP ----
__global__ __launch_bounds__(256) void k_sig(
        const float* __restrict__ x,
        const float* __restrict__ Wi0, const float* __restrict__ bi0,
        const float* __restrict__ Wi1, const float* __restrict__ bi1,
        const float* __restrict__ Wi2, const float* __restrict__ bi2) {
    const int b = blockIdx.x;
    const int tid = threadIdx.x;
    __shared__ float dxs[NW][WIN][D];
    __shared__ float cums[NW][WIN][D];
    __shared__ float ua[H], ub[H];

    const float* xb = x + (size_t)b * TT * D;

    if (tid < NW * D) {
        int w = tid / D, i = tid % D;
        float run = 0.f;
        float prev = xb[(w * WIN) * D + i];
        for (int k = 0; k < WIN; ++k) {
            float cur = xb[(w * WIN + k + 1) * D + i];
            float d = cur - prev; prev = cur;
            dxs[w][k][i] = d;
            cums[w][k][i] = run;
            run += d;
        }
        g_lvl1[(b * NW + w) * D + i] = run;
    }
    __syncthreads();
    for (int e = tid; e < NW * D * D; e += blockDim.x) {
        int w = e / (D * D); int rem = e % (D * D);
        int i = rem / D, j = rem % D;
        float s = 0.f;
        for (int k = 0; k < WIN; ++k)
            s += cums[w][k][i] * dxs[w][k][j] - cums[w][k][j] * dxs[w][k][i];
        g_area[(b * NW + w) * (D * D) + rem] = 0.5f * s;
    }
    if (tid < H) {
        float z = bi0[tid];
        for (int k = 0; k < D; ++k) z += Wi0[tid * D + k] * xb[k];
        ua[tid] = sp(z);
    }
    __syncthreads();
    if (tid < H) {
        float z = bi1[tid];
        for (int k = 0; k < H; ++k) z += Wi1[tid * H + k] * ua[k];
        ub[tid] = sp(z);
    }
    __syncthreads();
    if (tid < H) {
        float z = bi2[tid];
        for (int k = 0; k < H; ++k) z += Wi2[tid * H + k] * ub[k];
        g_h0[b * S + tid] = z;
    }
}

// ---- fully-resident W2: 24 NAMED float4/thread (3 rows x 8 quads) ----
#define FOR8(X) X(0) X(1) X(2) X(3) X(4) X(5) X(6) X(7)
#define DECL_W(i) float4 wA##i, wB##i, wC##i;
#define LOAD_W(i) wA##i = W24[bA + i]; wB##i = W24[bB + i]; wC##i = W24[bC + i];
#define C_Q(i) { float4 u = U24[i]; \
    acc0 = dot4(wA##i, u, acc0); acc1 = dot4(wB##i, u, acc1); acc2 = dot4(wC##i, u, acc2); }
#define G_Q(i) { \
    acc0 = dot4(wA##i, TAp[i], acc0); acc1 = dot4(wB##i, TBp[i], acc1); acc2 = dot4(wC##i, TCp[i], acc2); }

// ---- K3: the scan: 1024 threads (16 waves, 4/SIMD = native 128-VGPR point) ----
__global__ __launch_bounds__(1024) void k_scan(
        const float* __restrict__ bv0, const float* __restrict__ bv1,
        const float* __restrict__ bv2,
        const float* __restrict__ Wv0, const float* __restrict__ Wv1,
        const float* __restrict__ Wv2) {
    __shared__ float sm[SMTOT];
    const int b = blockIdx.x, tid = threadIdx.x;
    // 128-row matvec roles (A/B/E/F): 128 rows x 8 k-subs
    const int r8 = tid >> 3, ks = tid & 7;
    const int krow = r8 & 3;
    // W2 roles (C/G): R in [0,256), sub sp4 in [0,4) owns quads [8*sp4, 8*sp4+8)
    const int sp4 = tid & 3, R = tid >> 2;
    const int qo = sp4 * 8;
    const int jA = R >> 7;          // j of row R; rows R+256 -> 2+jA, R+512 -> 4+jA

    // stage W0, W1 (4096 float4 each), b2
    {
        float4* d = (float4*)(sm + O_W0);
        const float4* s0 = (const float4*)Wv0;
        const float4* s1 = (const float4*)Wv1;
        #pragma unroll
        for (int i = 0; i < 4; ++i) d[tid + i * 1024] = s0[tid + i * 1024];
        #pragma unroll
        for (int i = 0; i < 4; ++i) d[4096 + tid + i * 1024] = s1[tid + i * 1024];
        if (tid < 768) sm[O_B2 + tid] = bv2[tid];
    }
    // resident W2: rows R, R+256, R+512, quads [qo, qo+8)  = 96 VGPRs
    FOR8(DECL_W)
    const float4* W24 = (const float4*)Wv2;   // [768][32]
    const int bA = R * 32 + qo;
    const int bB = (R + 256) * 32 + qo;
    const int bC = (R + 512) * 32 + qo;
    FOR8(LOAD_W)
    if (tid < 128) {
        sm[O_B0 + tid] = bv0[tid]; sm[O_B1 + tid] = bv1[tid];
        float h0v = g_h0[b * 128 + tid];
        sm[O_H + tid] = h0v;
        g_hist[(b * (NW + 1)) * 128 + tid] = h0v;
    }
    if (tid >= 960) {               // sig for t=0 into buf 0
        int q = tid - 960;
        if (q < 42)
            sm[O_SIG + q] = (q < 6) ? g_lvl1[(b * NW) * 6 + q]
                                    : g_area[(b * NW) * 36 + q - 6];
    }
    __syncthreads();

    const float4* W04 = (const float4*)(sm + O_W0);
    const float4* W14 = (const float4*)(sm + O_W1);

    int p = 0;
    for (int t = 0; t < NW; ++t) {
        // prefetch sig for t+1 (written at H phase)
        float rsig = 0.f;
        if (tid >= 960) {
            int q = tid - 960;
            if (q < 42 && t + 1 < NW)
                rsig = (q < 6) ? g_lvl1[(b * NW + t + 1) * 6 + q]
                               : g_area[(b * NW + t + 1) * 36 + q - 6];
        }
        const int sb = O_SIG + (t & 1) * 44;

        // ---- A: z1 = W0.h -> u1, sg1 ----
        {
            float a = 0.f;
            const float4* H4 = (const float4*)(sm + O_H + p * 128);
            #pragma unroll
            for (int i = 0; i < 4; ++i) {
                int qq = ks * 4 + (i ^ krow);
                a = dot4(W04[r8 * 32 + qq], H4[qq], a);
            }
            a += __shfl_xor(a, 1); a += __shfl_xor(a, 2); a += __shfl_xor(a, 4);
            if (ks == 0)      sm[O_U1 + r8]  = sp(sm[O_B0 + r8] + a);
            else if (ks == 1) sm[O_SG1 + r8] = sigm(sm[O_B0 + r8] + a);
        }
        __syncthreads();
        // ---- B: z2 = W1.u1 -> u2, sg2 ----
        {
            float a = 0.f;
            const float4* U14 = (const float4*)(sm + O_U1);
            #pragma unroll
            for (int i = 0; i < 4; ++i) {
                int qq = ks * 4 + (i ^ krow);
                a = dot4(W14[r8 * 32 + qq], U14[qq], a);
            }
            a += __shfl_xor(a, 1); a += __shfl_xor(a, 2); a += __shfl_xor(a, 4);
            if (ks == 0)      sm[O_U2 + r8]  = sp(sm[O_B1 + r8] + a);
            else if (ks == 1) sm[O_SG2 + r8] = sigm(sm[O_B1 + r8] + a);
        }
        __syncthreads();
        // ---- C: V = tanh(W2.u2 + b2)  (register-resident W2) ----
        {
            float acc0 = 0.f, acc1 = 0.f, acc2 = 0.f;
            const float4* U24 = (const float4*)(sm + O_U2) + qo;
            FOR8(C_Q)
            acc0 += __shfl_xor(acc0, 1); acc0 += __shfl_xor(acc0, 2);
            acc1 += __shfl_xor(acc1, 1); acc1 += __shfl_xor(acc1, 2);
            acc2 += __shfl_xor(acc2, 1); acc2 += __shfl_xor(acc2, 2);
            if (sp4 == 0) {
                sm[O_V + R]       = tanhf(sm[O_B2 + R] + acc0);
                sm[O_V + R + 256] = tanhf(sm[O_B2 + R + 256] + acc1);
                sm[O_V + R + 512] = tanhf(sm[O_B2 + R + 512] + acc2);
            }
        }
        __syncthreads();
        // ---- D: U_j = sum_i area[i][j] V_i ; h-next init ----
        {
            if (tid < 768) {
                int jj = tid >> 7, rr = tid & 127;
                float u = 0.f;
                #pragma unroll
                for (int i = 0; i < 6; ++i)
                    u = fmaf(sm[sb + 6 + i * 6 + jj], sm[O_V + i * 128 + rr], u);
                sm[O_U + jj * 128 + rr] = u;
            } else if (tid < 896) {
                int tt = tid - 768;
                float xh = sm[O_H + p * 128 + tt];
                #pragma unroll
                for (int i = 0; i < 6; ++i)
                    xh = fmaf(sm[sb + i], sm[O_V + i * 128 + tt], xh);
                sm[O_H + (p ^ 1) * 128 + tt] = xh;
            }
        }
        __syncthreads();
        // ---- E: T1_j = sg1 .* (W0 U_j)  128 rows x 8 ks, 6 j's ----
        {
            float a0 = 0, a1 = 0, a2 = 0, a3 = 0, a4 = 0, a5 = 0;
            const float4* U4 = (const float4*)(sm + O_U);
            #pragma unroll
            for (int i = 0; i < 4; ++i) {
                int qq = ks * 4 + (i ^ krow);
                float4 w = W04[r8 * 32 + qq];
                a0 = dot4(w, U4[qq], a0);
                a1 = dot4(w, U4[32 + qq], a1);
                a2 = dot4(w, U4[64 + qq], a2);
                a3 = dot4(w, U4[96 + qq], a3);
                a4 = dot4(w, U4[128 + qq], a4);
                a5 = dot4(w, U4[160 + qq], a5);
            }
            a0 += __shfl_xor(a0, 1); a0 += __shfl_xor(a0, 2); a0 += __shfl_xor(a0, 4);
            a1 += __shfl_xor(a1, 1); a1 += __shfl_xor(a1, 2); a1 += __shfl_xor(a1, 4);
            a2 += __shfl_xor(a2, 1); a2 += __shfl_xor(a2, 2); a2 += __shfl_xor(a2, 4);
            a3 += __shfl_xor(a3, 1); a3 += __shfl_xor(a3, 2); a3 += __shfl_xor(a3, 4);
            a4 += __shfl_xor(a4, 1); a4 += __shfl_xor(a4, 2); a4 += __shfl_xor(a4, 4);
            a5 += __shfl_xor(a5, 1); a5 += __shfl_xor(a5, 2); a5 += __shfl_xor(a5, 4);
            if (ks == 0) {
                float sg = sm[O_SG1 + r8];
                sm[O_TB + 0 * 128 + r8] = sg * a0;
                sm[O_TB + 1 * 128 + r8] = sg * a1;
                sm[O_TB + 2 * 128 + r8] = sg * a2;
                sm[O_TB + 3 * 128 + r8] = sg * a3;
                sm[O_TB + 4 * 128 + r8] = sg * a4;
                sm[O_TB + 5 * 128 + r8] = sg * a5;
            }
        }
        __syncthreads();
        // ---- F: T2_j = sg2 .* (W1 T1_j)  (into O_U) ----
        {
            float a0 = 0, a1 = 0, a2 = 0, a3 = 0, a4 = 0, a5 = 0;
            const float4* T4 = (const float4*)(sm + O_TB);
            #pragma unroll
            for (int i = 0; i < 4; ++i) {
                int qq = ks * 4 + (i ^ krow);
                float4 w = W14[r8 * 32 + qq];
                a0 = dot4(w, T4[qq], a0);
                a1 = dot4(w, T4[32 + qq], a1);
                a2 = dot4(w, T4[64 + qq], a2);
                a3 = dot4(w, T4[96 + qq], a3);
                a4 = dot4(w, T4[128 + qq], a4);
                a5 = dot4(w, T4[160 + qq], a5);
            }
            a0 += __shfl_xor(a0, 1); a0 += __shfl_xor(a0, 2); a0 += __shfl_xor(a0, 4);
            a1 += __shfl_xor(a1, 1); a1 += __shfl_xor(a1, 2); a1 += __shfl_xor(a1, 4);
            a2 += __shfl_xor(a2, 1); a2 += __shfl_xor(a2, 2); a2 += __shfl_xor(a2, 4);
            a3 += __shfl_xor(a3, 1); a3 += __shfl_xor(a3, 2); a3 += __shfl_xor(a3, 4);
            a4 += __shfl_xor(a4, 1); a4 += __shfl_xor(a4, 2); a4 += __shfl_xor(a4, 4);
            a5 += __shfl_xor(a5, 1); a5 += __shfl_xor(a5, 2); a5 += __shfl_xor(a5, 4);
            if (ks == 0) {
                float sg = sm[O_SG2 + r8];
                sm[O_U + 0 * 128 + r8] = sg * a0;
                sm[O_U + 1 * 128 + r8] = sg * a1;
                sm[O_U + 2 * 128 + r8] = sg * a2;
                sm[O_U + 3 * 128 + r8] = sg * a3;
                sm[O_U + 4 * 128 + r8] = sg * a4;
                sm[O_U + 5 * 128 + r8] = sg * a5;
            }
        }
        __syncthreads();
        // ---- G: bterm = (1-V^2).*(W2 T2_j(row))  (into O_TB) ----
        {
            float acc0 = 0.f, acc1 = 0.f, acc2 = 0.f;
            const float4* TAp = (const float4*)(sm + O_U) + jA * 32 + qo;
            const float4* TBp = (const float4*)(sm + O_U) + (2 + jA) * 32 + qo;
            const float4* TCp = (const float4*)(sm + O_U) + (4 + jA) * 32 + qo;
            FOR8(G_Q)
            acc0 += __shfl_xor(acc0, 1); acc0 += __shfl_xor(acc0, 2);
            acc1 += __shfl_xor(acc1, 1); acc1 += __shfl_xor(acc1, 2);
            acc2 += __shfl_xor(acc2, 1); acc2 += __shfl_xor(acc2, 2);
            if (sp4 == 0) {
                float v0 = sm[O_V + R];
                float v1 = sm[O_V + R + 256];
                float v2 = sm[O_V + R + 512];
                sm[O_TB + R]       = (1.f - v0 * v0) * acc0;
                sm[O_TB + R + 256] = (1.f - v1 * v1) * acc1;
                sm[O_TB + R + 512] = (1.f - v2 * v2) * acc2;
            }
        }
        __syncthreads();
        // ---- H: h update + hist; store prefetched sig ----
        if (tid < 128) {
            float xh = sm[O_H + (p ^ 1) * 128 + tid];
            #pragma unroll
            for (int j = 0; j < 6; ++j) xh += sm[O_TB + j * 128 + tid];
            sm[O_H + (p ^ 1) * 128 + tid] = xh;
            g_hist[(b * (NW + 1) + t + 1) * 128 + tid] = xh;
        }
        if (tid >= 960) {
            int q = tid - 960;
            if (q < 42 && t + 1 < NW)
                sm[O_SIG + ((t + 1) & 1) * 44 + q] = rsig;
        }
        p ^= 1;
        __syncthreads();
    }
}

// ---- K4: readout ----
__global__ __launch_bounds__(384) void k_read(const float* __restrict__ Wr,
                                              const float* __restrict__ br,
                                              float* __restrict__ out) {
    const int b = blockIdx.x, e = threadIdx.x;
    if (e < (NW + 1) * OUTD) {
        int t = e / OUTD, o = e % OUTD;
        float z = br[o];
        const float4* hrow = (const float4*)&g_hist[(b * (NW + 1) + t) * 128];
        const float4* wrow = (const float4*)&Wr[o * 128];
        float z0 = 0, z1 = 0, z2 = 0, z3 = 0;
        #pragma unroll 8
        for (int s4 = 0; s4 < 32; ++s4) {
            float4 hv = hrow[s4]; float4 wv = wrow[s4];
            z0 = fmaf(hv.x, wv.x, z0); z1 = fmaf(hv.y, wv.y, z1);
            z2 = fmaf(hv.z, wv.z, z2); z3 = fmaf(hv.w, wv.w, z3);
        }
        out[(b * (NW + 1) + t) * OUTD + o] = z + ((z0 + z1) + (z2 + z3));
    }
}

extern "C" void kernel_launch(void* const* d_in, const int* in_sizes, int n_in,
                              void* d_out, int out_size, void* d_ws, size_t ws_size,
                              hipStream_t stream) {
    const float* x   = (const float*)d_in[0];
    const float* Wi0 = (const float*)d_in[1];
    const float* bi0 = (const float*)d_in[2];
    const float* Wi1 = (const float*)d_in[3];
    const float* bi1 = (const float*)d_in[4];
    const float* Wi2 = (const float*)d_in[5];
    const float* bi2 = (const float*)d_in[6];
    const float* Wv0 = (const float*)d_in[7];
    const float* bv0 = (const float*)d_in[8];
    const float* Wv1 = (const float*)d_in[9];
    const float* bv1 = (const float*)d_in[10];
    const float* Wv2 = (const float*)d_in[11];
    const float* bv2 = (const float*)d_in[12];
    const float* Wr  = (const float*)d_in[13];
    const float* br  = (const float*)d_in[14];
    float* out = (float*)d_out;

    hipLaunchKernelGGL(k_sig,  dim3(BB), dim3(256),  0, stream,
                       x, Wi0, bi0, Wi1, bi1, Wi2, bi2);
    hipLaunchKernelGGL(k_scan, dim3(BB), dim3(1024), 0, stream,
                       bv0, bv1, bv2, Wv0, Wv1, Wv2);
    hipLaunchKernelGGL(k_read, dim3(BB), dim3(384),  0, stream, Wr, br, out);
}

// Round 13
// 524.365 us; speedup vs baseline: 1.0070x; 1.0070x over previous
//
#include <hip/hip_runtime.h>
#include <math.h>

#define D    6
#define S    128
#define H    128
#define WIN  16
#define BB   8
#define TT   513
#define NW   32
#define OUTD 10

// ---- device-global scratch ----
__device__ float g_lvl1[BB * NW * D];
__device__ float g_area[BB * NW * D * D];
__device__ float g_h0[BB * S];
__device__ float g_hist[BB * (NW + 1) * S];

__device__ __forceinline__ float sp(float x) {
    return (x > 20.f) ? x : log1pf(expf(x));
}
__device__ __forceinline__ float sigm(float x) {
    return 1.f / (1.f + expf(-x));
}
__device__ __forceinline__ float dot4(float4 a, float4 b, float acc) {
    return fmaf(a.x, b.x, fmaf(a.y, b.y, fmaf(a.z, b.z, fmaf(a.w, b.w, acc))));
}

// ---- LDS layout (float offsets) ----
#define O_W0   0        // [128 r][128 k] fp32 row-major
#define O_W1   16384    // -> 32768
#define O_U1   32768    // u1 [128]
#define O_SG1  32896
#define O_U2   33024
#define O_SG2  33152
#define O_V    33280    // [768]
#define O_U    34048    // [6][128]: U tangents, then T2
#define O_TB   34816    // [6][128]: T1, then bterm [768]
#define O_H    35584    // h double buffer [2][128]
#define O_B0   35840
#define O_B1   35968
#define O_B2   36096    // [768]
#define O_SIG  36864    // [2][44]
#define SMTOT  36952    // 147,808 B

// ---- K2: windowed log-signature + init MLP ----
__global__ __launch_bounds__(256) void k_sig(
        const float* __restrict__ x,
        const float* __restrict__ Wi0, const float* __restrict__ bi0,
        const float* __restrict__ Wi1, const float* __restrict__ bi1,
        const float* __restrict__ Wi2, const float* __restrict__ bi2) {
    const int b = blockIdx.x;
    const int tid = threadIdx.x;
    __shared__ float dxs[NW][WIN][D];
    __shared__ float cums[NW][WIN][D];
    __shared__ float ua[H], ub[H];

    const float* xb = x + (size_t)b * TT * D;

    if (tid < NW * D) {
        int w = tid / D, i = tid % D;
        float run = 0.f;
        float prev = xb[(w * WIN) * D + i];
        for (int k = 0; k < WIN; ++k) {
            float cur = xb[(w * WIN + k + 1) * D + i];
            float d = cur - prev; prev = cur;
            dxs[w][k][i] = d;
            cums[w][k][i] = run;
            run += d;
        }
        g_lvl1[(b * NW + w) * D + i] = run;
    }
    __syncthreads();
    for (int e = tid; e < NW * D * D; e += blockDim.x) {
        int w = e / (D * D); int rem = e % (D * D);
        int i = rem / D, j = rem % D;
        float s = 0.f;
        for (int k = 0; k < WIN; ++k)
            s += cums[w][k][i] * dxs[w][k][j] - cums[w][k][j] * dxs[w][k][i];
        g_area[(b * NW + w) * (D * D) + rem] = 0.5f * s;
    }
    if (tid < H) {
        float z = bi0[tid];
        for (int k = 0; k < D; ++k) z += Wi0[tid * D + k] * xb[k];
        ua[tid] = sp(z);
    }
    __syncthreads();
    if (tid < H) {
        float z = bi1[tid];
        for (int k = 0; k < H; ++k) z += Wi1[tid * H + k] * ua[k];
        ub[tid] = sp(z);
    }
    __syncthreads();
    if (tid < H) {
        float z = bi2[tid];
        for (int k = 0; k < H; ++k) z += Wi2[tid * H + k] * ub[k];
        g_h0[b * S + tid] = z;
    }
}

// ---- K3: the scan: 1024 threads; W2 streamed from L2 (no residency demands) ----
__global__ __launch_bounds__(1024) void k_scan(
        const float* __restrict__ bv0, const float* __restrict__ bv1,
        const float* __restrict__ bv2,
        const float* __restrict__ Wv0, const float* __restrict__ Wv1,
        const float* __restrict__ Wv2) {
    __shared__ float sm[SMTOT];
    const int b = blockIdx.x, tid = threadIdx.x;
    // 128-row matvec roles (A/B/E/F): 128 rows x 8 k-subs
    const int r8 = tid >> 3, ks = tid & 7;
    const int krow = r8 & 3;
    // W2 roles (C/G): R in [0,256), sp4 owns quads [8*sp4, 8*sp4+8)
    const int sp4 = tid & 3, R = tid >> 2;
    const int qo = sp4 * 8;
    const int jA = R >> 7;          // j of row R; rows R+256 -> 2+jA, R+512 -> 4+jA

    // stage W0, W1 (4096 float4 each), b2
    {
        float4* d = (float4*)(sm + O_W0);
        const float4* s0 = (const float4*)Wv0;
        const float4* s1 = (const float4*)Wv1;
        #pragma unroll
        for (int i = 0; i < 4; ++i) d[tid + i * 1024] = s0[tid + i * 1024];
        #pragma unroll
        for (int i = 0; i < 4; ++i) d[4096 + tid + i * 1024] = s1[tid + i * 1024];
        if (tid < 768) sm[O_B2 + tid] = bv2[tid];
    }
    // W2 streaming pointers: rows R, R+256, R+512, quads [qo, qo+8)
    const float4* W24 = (const float4*)Wv2;   // [768][32]
    const float4* WA = W24 + (R * 32 + qo);
    const float4* WB = W24 + ((R + 256) * 32 + qo);
    const float4* WC = W24 + ((R + 512) * 32 + qo);
    if (tid < 128) {
        sm[O_B0 + tid] = bv0[tid]; sm[O_B1 + tid] = bv1[tid];
        float h0v = g_h0[b * 128 + tid];
        sm[O_H + tid] = h0v;
        g_hist[(b * (NW + 1)) * 128 + tid] = h0v;
    }
    if (tid >= 960) {               // sig for t=0 into buf 0
        int q = tid - 960;
        if (q < 42)
            sm[O_SIG + q] = (q < 6) ? g_lvl1[(b * NW) * 6 + q]
                                    : g_area[(b * NW) * 36 + q - 6];
    }
    __syncthreads();

    const float4* W04 = (const float4*)(sm + O_W0);
    const float4* W14 = (const float4*)(sm + O_W1);

    int p = 0;
    for (int t = 0; t < NW; ++t) {
        // prefetch sig for t+1 (written at H phase)
        float rsig = 0.f;
        if (tid >= 960) {
            int q = tid - 960;
            if (q < 42 && t + 1 < NW)
                rsig = (q < 6) ? g_lvl1[(b * NW + t + 1) * 6 + q]
                               : g_area[(b * NW + t + 1) * 36 + q - 6];
        }
        const int sb = O_SIG + (t & 1) * 44;

        // ---- A: z1 = W0.h -> u1, sg1 ----
        {
            float a = 0.f;
            const float4* H4 = (const float4*)(sm + O_H + p * 128);
            #pragma unroll
            for (int i = 0; i < 4; ++i) {
                int qq = ks * 4 + (i ^ krow);
                a = dot4(W04[r8 * 32 + qq], H4[qq], a);
            }
            a += __shfl_xor(a, 1); a += __shfl_xor(a, 2); a += __shfl_xor(a, 4);
            if (ks == 0)      sm[O_U1 + r8]  = sp(sm[O_B0 + r8] + a);
            else if (ks == 1) sm[O_SG1 + r8] = sigm(sm[O_B0 + r8] + a);
        }
        __syncthreads();
        // ---- B: z2 = W1.u1 -> u2, sg2 ----
        {
            float a = 0.f;
            const float4* U14 = (const float4*)(sm + O_U1);
            #pragma unroll
            for (int i = 0; i < 4; ++i) {
                int qq = ks * 4 + (i ^ krow);
                a = dot4(W14[r8 * 32 + qq], U14[qq], a);
            }
            a += __shfl_xor(a, 1); a += __shfl_xor(a, 2); a += __shfl_xor(a, 4);
            if (ks == 0)      sm[O_U2 + r8]  = sp(sm[O_B1 + r8] + a);
            else if (ks == 1) sm[O_SG2 + r8] = sigm(sm[O_B1 + r8] + a);
        }
        __syncthreads();
        // ---- C: V = tanh(W2.u2 + b2)  (W2 streamed from L2) ----
        {
            float acc0 = 0.f, acc1 = 0.f, acc2 = 0.f;
            const float4* U24 = (const float4*)(sm + O_U2) + qo;
            #pragma unroll
            for (int i = 0; i < 8; ++i) {
                float4 u = U24[i];
                acc0 = dot4(WA[i], u, acc0);
                acc1 = dot4(WB[i], u, acc1);
                acc2 = dot4(WC[i], u, acc2);
            }
            acc0 += __shfl_xor(acc0, 1); acc0 += __shfl_xor(acc0, 2);
            acc1 += __shfl_xor(acc1, 1); acc1 += __shfl_xor(acc1, 2);
            acc2 += __shfl_xor(acc2, 1); acc2 += __shfl_xor(acc2, 2);
            if (sp4 == 0) {
                sm[O_V + R]       = tanhf(sm[O_B2 + R] + acc0);
                sm[O_V + R + 256] = tanhf(sm[O_B2 + R + 256] + acc1);
                sm[O_V + R + 512] = tanhf(sm[O_B2 + R + 512] + acc2);
            }
        }
        __syncthreads();
        // ---- D: U_j = sum_i area[i][j] V_i ; h-next init ----
        {
            if (tid < 768) {
                int jj = tid >> 7, rr = tid & 127;
                float u = 0.f;
                #pragma unroll
                for (int i = 0; i < 6; ++i)
                    u = fmaf(sm[sb + 6 + i * 6 + jj], sm[O_V + i * 128 + rr], u);
                sm[O_U + jj * 128 + rr] = u;
            } else if (tid < 896) {
                int tt = tid - 768;
                float xh = sm[O_H + p * 128 + tt];
                #pragma unroll
                for (int i = 0; i < 6; ++i)
                    xh = fmaf(sm[sb + i], sm[O_V + i * 128 + tt], xh);
                sm[O_H + (p ^ 1) * 128 + tt] = xh;
            }
        }
        __syncthreads();
        // ---- E: T1_j = sg1 .* (W0 U_j)  128 rows x 8 ks, 6 j's ----
        {
            float a0 = 0, a1 = 0, a2 = 0, a3 = 0, a4 = 0, a5 = 0;
            const float4* U4 = (const float4*)(sm + O_U);
            #pragma unroll
            for (int i = 0; i < 4; ++i) {
                int qq = ks * 4 + (i ^ krow);
                float4 w = W04[r8 * 32 + qq];
                a0 = dot4(w, U4[qq], a0);
                a1 = dot4(w, U4[32 + qq], a1);
                a2 = dot4(w, U4[64 + qq], a2);
                a3 = dot4(w, U4[96 + qq], a3);
                a4 = dot4(w, U4[128 + qq], a4);
                a5 = dot4(w, U4[160 + qq], a5);
            }
            a0 += __shfl_xor(a0, 1); a0 += __shfl_xor(a0, 2); a0 += __shfl_xor(a0, 4);
            a1 += __shfl_xor(a1, 1); a1 += __shfl_xor(a1, 2); a1 += __shfl_xor(a1, 4);
            a2 += __shfl_xor(a2, 1); a2 += __shfl_xor(a2, 2); a2 += __shfl_xor(a2, 4);
            a3 += __shfl_xor(a3, 1); a3 += __shfl_xor(a3, 2); a3 += __shfl_xor(a3, 4);
            a4 += __shfl_xor(a4, 1); a4 += __shfl_xor(a4, 2); a4 += __shfl_xor(a4, 4);
            a5 += __shfl_xor(a5, 1); a5 += __shfl_xor(a5, 2); a5 += __shfl_xor(a5, 4);
            if (ks == 0) {
                float sg = sm[O_SG1 + r8];
                sm[O_TB + 0 * 128 + r8] = sg * a0;
                sm[O_TB + 1 * 128 + r8] = sg * a1;
                sm[O_TB + 2 * 128 + r8] = sg * a2;
                sm[O_TB + 3 * 128 + r8] = sg * a3;
                sm[O_TB + 4 * 128 + r8] = sg * a4;
                sm[O_TB + 5 * 128 + r8] = sg * a5;
            }
        }
        __syncthreads();
        // ---- F: T2_j = sg2 .* (W1 T1_j)  (into O_U) ----
        {
            float a0 = 0, a1 = 0, a2 = 0, a3 = 0, a4 = 0, a5 = 0;
            const float4* T4 = (const float4*)(sm + O_TB);
            #pragma unroll
            for (int i = 0; i < 4; ++i) {
                int qq = ks * 4 + (i ^ krow);
                float4 w = W14[r8 * 32 + qq];
                a0 = dot4(w, T4[qq], a0);
                a1 = dot4(w, T4[32 + qq], a1);
                a2 = dot4(w, T4[64 + qq], a2);
                a3 = dot4(w, T4[96 + qq], a3);
                a4 = dot4(w, T4[128 + qq], a4);
                a5 = dot4(w, T4[160 + qq], a5);
            }
            a0 += __shfl_xor(a0, 1); a0 += __shfl_xor(a0, 2); a0 += __shfl_xor(a0, 4);
            a1 += __shfl_xor(a1, 1); a1 += __shfl_xor(a1, 2); a1 += __shfl_xor(a1, 4);
            a2 += __shfl_xor(a2, 1); a2 += __shfl_xor(a2, 2); a2 += __shfl_xor(a2, 4);
            a3 += __shfl_xor(a3, 1); a3 += __shfl_xor(a3, 2); a3 += __shfl_xor(a3, 4);
            a4 += __shfl_xor(a4, 1); a4 += __shfl_xor(a4, 2); a4 += __shfl_xor(a4, 4);
            a5 += __shfl_xor(a5, 1); a5 += __shfl_xor(a5, 2); a5 += __shfl_xor(a5, 4);
            if (ks == 0) {
                float sg = sm[O_SG2 + r8];
                sm[O_U + 0 * 128 + r8] = sg * a0;
                sm[O_U + 1 * 128 + r8] = sg * a1;
                sm[O_U + 2 * 128 + r8] = sg * a2;
                sm[O_U + 3 * 128 + r8] = sg * a3;
                sm[O_U + 4 * 128 + r8] = sg * a4;
                sm[O_U + 5 * 128 + r8] = sg * a5;
            }
        }
        __syncthreads();
        // ---- G: bterm = (1-V^2).*(W2 T2_j(row))  (W2 streamed, into O_TB) ----
        {
            float acc0 = 0.f, acc1 = 0.f, acc2 = 0.f;
            const float4* TAp = (const float4*)(sm + O_U) + jA * 32 + qo;
            const float4* TBp = (const float4*)(sm + O_U) + (2 + jA) * 32 + qo;
            const float4* TCp = (const float4*)(sm + O_U) + (4 + jA) * 32 + qo;
            #pragma unroll
            for (int i = 0; i < 8; ++i) {
                acc0 = dot4(WA[i], TAp[i], acc0);
                acc1 = dot4(WB[i], TBp[i], acc1);
                acc2 = dot4(WC[i], TCp[i], acc2);
            }
            acc0 += __shfl_xor(acc0, 1); acc0 += __shfl_xor(acc0, 2);
            acc1 += __shfl_xor(acc1, 1); acc1 += __shfl_xor(acc1, 2);
            acc2 += __shfl_xor(acc2, 1); acc2 += __shfl_xor(acc2, 2);
            if (sp4 == 0) {
                float v0 = sm[O_V + R];
                float v1 = sm[O_V + R + 256];
                float v2 = sm[O_V + R + 512];
                sm[O_TB + R]       = (1.f - v0 * v0) * acc0;
                sm[O_TB + R + 256] = (1.f - v1 * v1) * acc1;
                sm[O_TB + R + 512] = (1.f - v2 * v2) * acc2;
            }
        }
        __syncthreads();
        // ---- H: h update + hist; store prefetched sig ----
        if (tid < 128) {
            float xh = sm[O_H + (p ^ 1) * 128 + tid];
            #pragma unroll
            for (int j = 0; j < 6; ++j) xh += sm[O_TB + j * 128 + tid];
            sm[O_H + (p ^ 1) * 128 + tid] = xh;
            g_hist[(b * (NW + 1) + t + 1) * 128 + tid] = xh;
        }
        if (tid >= 960) {
            int q = tid - 960;
            if (q < 42 && t + 1 < NW)
                sm[O_SIG + ((t + 1) & 1) * 44 + q] = rsig;
        }
        p ^= 1;
        __syncthreads();
    }
}

// ---- K4: readout ----
__global__ __launch_bounds__(384) void k_read(const float* __restrict__ Wr,
                                              const float* __restrict__ br,
                                              float* __restrict__ out) {
    const int b = blockIdx.x, e = threadIdx.x;
    if (e < (NW + 1) * OUTD) {
        int t = e / OUTD, o = e % OUTD;
        float z = br[o];
        const float4* hrow = (const float4*)&g_hist[(b * (NW + 1) + t) * 128];
        const float4* wrow = (const float4*)&Wr[o * 128];
        float z0 = 0, z1 = 0, z2 = 0, z3 = 0;
        #pragma unroll 8
        for (int s4 = 0; s4 < 32; ++s4) {
            float4 hv = hrow[s4]; float4 wv = wrow[s4];
            z0 = fmaf(hv.x, wv.x, z0); z1 = fmaf(hv.y, wv.y, z1);
            z2 = fmaf(hv.z, wv.z, z2); z3 = fmaf(hv.w, wv.w, z3);
        }
        out[(b * (NW + 1) + t) * OUTD + o] = z + ((z0 + z1) + (z2 + z3));
    }
}

extern "C" void kernel_launch(void* const* d_in, const int* in_sizes, int n_in,
                              void* d_out, int out_size, void* d_ws, size_t ws_size,
                              hipStream_t stream) {
    const float* x   = (const float*)d_in[0];
    const float* Wi0 = (const float*)d_in[1];
    const float* bi0 = (const float*)d_in[2];
    const float* Wi1 = (const float*)d_in[3];
    const float* bi1 = (const float*)d_in[4];
    const float* Wi2 = (const float*)d_in[5];
    const float* bi2 = (const float*)d_in[6];
    const float* Wv0 = (const float*)d_in[7];
    const float* bv0 = (const float*)d_in[8];
    const float* Wv1 = (const float*)d_in[9];
    const float* bv1 = (const float*)d_in[10];
    const float* Wv2 = (const float*)d_in[11];
    const float* bv2 = (const float*)d_in[12];
    const float* Wr  = (const float*)d_in[13];
    const float* br  = (const float*)d_in[14];
    float* out = (float*)d_out;

    hipLaunchKernelGGL(k_sig,  dim3(BB), dim3(256),  0, stream,
                       x, Wi0, bi0, Wi1, bi1, Wi2, bi2);
    hipLaunchKernelGGL(k_scan, dim3(BB), dim3(1024), 0, stream,
                       bv0, bv1, bv2, Wv0, Wv1, Wv2);
    hipLaunchKernelGGL(k_read, dim3(BB), dim3(384),  0, stream, Wr, br, out);
}